// Round 3
// 173.560 us; speedup vs baseline: 1.1015x; 1.1015x over previous
//
#include <hip/hip_runtime.h>

// Shapes: B=16, S=1024, E=64, H=8, d=8, INPUT_DIM=310
// local mask: |i-j|<=5 (11 keys); sparse mask: j%3==0 or i==j (342 keys + diag)
//
// R13 = R12 with the prep_w VT-pad bug fixed (coverage was 16/128 bh panels).
// Structure (5 dispatches):
//  1. prep_w        — weight split + fused fusion W + bc + numden zero + VT pads
//  2. gemm_proj_qkv — proj GEMM -> xp tile in LDS (bf16 hi/lo) -> qkv GEMM both
//                     branches; epilogue writes qkv_l/qkv_g fp32 AND K/V bf16
//                     split buffers directly from accumulators (repack deleted)
//  3. attn          — global MFMA attention (2048 blocks) + local attention
//                     (512 blocks) in one launch (independent work)
//  4. gemm_fuse_score
//  5. finalize
// GEMMs + global attention via mfma_f32_16x16x32_bf16, fp32 = hi+lo bf16 split.
// A-frag A[m=lane&15][k=quad*8+j]; B-frag B[n=lane&15][k=quad*8+j];
// C/D: col=lane&15, row=quad*4+reg.

typedef __attribute__((ext_vector_type(8))) short short8;
typedef __attribute__((ext_vector_type(4))) float float4v;

#define INV_SQRT8 0.3535533905932738f

__device__ __forceinline__ float4 ld4(const float* p) { return *(const float4*)p; }

__device__ __forceinline__ float4 f4fma(float s, float4 w, float4 a) {
  a.x = fmaf(s, w.x, a.x); a.y = fmaf(s, w.y, a.y);
  a.z = fmaf(s, w.z, a.z); a.w = fmaf(s, w.w, a.w);
  return a;
}

// RNE fp32 -> (bf16 hi, bf16 lo); x == hi + lo to ~2^-16 relative.
__device__ __forceinline__ void bsplit(float x, short& h, short& l) {
  unsigned xb = __float_as_uint(x);
  unsigned hb = (xb + 0x7fffu + ((xb >> 16) & 1u)) & 0xffff0000u;
  h = (short)(hb >> 16);
  float lf = x - __uint_as_float(hb);
  unsigned lb = __float_as_uint(lf);
  l = (short)((lb + 0x7fffu + ((lb >> 16) & 1u)) >> 16);
}

// ---------------- prep_w: split weights + fused fusion weights + bc + zero
// num/den + VT constant pads (ones row n=8, zero rows n>8, kk>=342 pads).
// idx map: [0,53248) weights; [53248, 53248+360448) VT n in [8,16) for ALL
// 128 bh panels; next 10240 = VT n<8 kk in [342,352) zero pads.
__global__ __launch_bounds__(256) void prep_w(
    const float* __restrict__ pw, const float* __restrict__ liw,
    const float* __restrict__ giw, const float* __restrict__ fw,
    const float* __restrict__ low, const float* __restrict__ gow,
    const float* __restrict__ lob, const float* __restrict__ gob,
    const float* __restrict__ fb,
    short* __restrict__ wb, float* __restrict__ bc, float* __restrict__ numden,
    short* __restrict__ VTh, short* __restrict__ VTl)
{
  unsigned idx = blockIdx.x * 256 + threadIdx.x;
  if (idx < 53248u) {
    float v; unsigned ho, lo_;
    if (idx < 20480u) {           // proj, padded K 310->320
      unsigned r = idx / 320u, k = idx - r * 320u;
      v = (k < 310u) ? pw[r * 310u + k] : 0.f;
      ho = 0u + idx; lo_ = 20480u + idx;
    } else if (idx < 32768u) {    // loc_in
      unsigned i = idx - 20480u; v = liw[i]; ho = 40960u + i; lo_ = 53248u + i;
    } else if (idx < 45056u) {    // glob_in
      unsigned i = idx - 32768u; v = giw[i]; ho = 65536u + i; lo_ = 77824u + i;
    } else {                      // fused fusion weight W12[n][k]
      unsigned i = idx - 45056u;
      unsigned n = i >> 7, k = i & 127u;
      float s = 0.f;
      if (k < 64u) {
        for (int e = 0; e < 64; e++) s += fw[n * 128 + e] * low[e * 64 + k];
      } else {
        for (int e = 0; e < 64; e++) s += fw[n * 128 + 64 + e] * gow[e * 64 + (k - 64u)];
      }
      v = s; ho = 90112u + i; lo_ = 98304u + i;
    }
    short h, l; bsplit(v, h, l);
    wb[ho] = h; wb[lo_] = l;
    if (idx < 64u) {
      float b = fb[idx];
      for (int e = 0; e < 64; e++)
        b += lob[e] * fw[idx * 128 + e] + gob[e] * fw[idx * 128 + 64 + e];
      bc[idx] = b;
    }
    if (idx < 1040u) numden[idx] = 0.f;   // num[1024] + den[16]
  } else {
    // VT constant pads. Data rows (n<8, kk<342) come from gemm_proj_qkv.
    unsigned t = idx - 53248u;
    if (t < 370688u) {
      unsigned pos; short hv = 0;
      if (t < 360448u) {                // n in [8,16): ones row / zeros, 128 bh
        unsigned bh = t / 2816u;        // 8*352
        unsigned rem = t - bh * 2816u;
        unsigned n8 = rem / 352u;
        unsigned kk = rem - n8 * 352u;
        pos = (bh * 16u + 8u + n8) * 352u + kk;
        if (n8 == 0u) hv = (short)0x3F80;   // bf16(1.0)
      } else {                          // n<8, kk in [342,352): zero pad
        unsigned t2 = t - 360448u;      // < 10240
        unsigned bh = t2 / 80u;
        unsigned rem = t2 - bh * 80u;
        unsigned n = rem / 10u;
        unsigned kk = 342u + (rem - n * 10u);
        pos = (bh * 16u + n) * 352u + kk;
      }
      VTh[pos] = hv; VTl[pos] = 0;
    }
  }
}

// ---------------- fused proj + qkv GEMM.
// Block = 64 rows, 4 waves; wave w owns rows m0+w*16..+16 end-to-end:
//   phase A: xp = x @ proj_w^T + proj_b (fp32 A in-register, 4 col-frags)
//            -> bf16 hi/lo into LDS (wave-local rows => no barrier).
//            Row pad 72 shorts: 144B stride keeps ds_read_b128 16B-aligned,
//            bank aliasing <= 2-way (free).
//   phase B: qkv = xp @ Win^T + bin for BOTH branches (24 col-frags, K=64).
//   epilogue: qkv_l/qkv_g fp32; rows i%3==0 of global branch additionally
//            bsplit from the accumulator straight into KH/KL (K[key][d]) and
//            VTh/VTl (V^T[d][key]) — bit-identical to the old repack.
__global__ __launch_bounds__(256) void gemm_proj_qkv(
    const float* __restrict__ X,
    const short* __restrict__ PWh, const short* __restrict__ PWl,
    const float* __restrict__ pb,
    const short* __restrict__ LWh, const short* __restrict__ LWl,
    const short* __restrict__ GWh, const short* __restrict__ GWl,
    const float* __restrict__ lb, const float* __restrict__ gb,
    float* __restrict__ qkv_l, float* __restrict__ qkv_g,
    short* __restrict__ KH, short* __restrict__ KL,
    short* __restrict__ VTh, short* __restrict__ VTl)
{
  __shared__ __align__(16) short XPH[64][72];
  __shared__ __align__(16) short XPL[64][72];
  const int lane = threadIdx.x & 63;
  const int w = threadIdx.x >> 6;
  const int q = lane >> 4, r = lane & 15;
  const int mloc = w * 16;
  const int m0 = blockIdx.x * 64 + mloc;

  // ---- phase A: proj
  float4v accp[4];
  #pragma unroll
  for (int g = 0; g < 4; g++) {
    float bv = pb[g * 16 + r];
    float4v t = {bv, bv, bv, bv};
    accp[g] = t;
  }
  const float* arow = X + (size_t)(m0 + r) * 310;
  #pragma unroll
  for (int ks = 0; ks < 10; ks++) {
    const int k0 = ks * 32 + q * 8;
    float av[8];
    if (ks < 9) {
      const float* ap = arow + k0;
      #pragma unroll
      for (int t = 0; t < 4; t++) {
        float2 f = *(const float2*)(ap + t * 2);
        av[t*2] = f.x; av[t*2+1] = f.y;
      }
    } else {
      #pragma unroll
      for (int j = 0; j < 8; j++) {
        int kidx = k0 + j;
        av[j] = (kidx < 310) ? arow[kidx] : 0.f;
      }
    }
    short8 ah, al;
    #pragma unroll
    for (int i = 0; i < 8; i++) { short h, l; bsplit(av[i], h, l); ah[i]=h; al[i]=l; }
    #pragma unroll
    for (int g = 0; g < 4; g++) {
      short8 bh = *(const short8*)(PWh + (size_t)(g * 16 + r) * 320 + k0);
      short8 bl = *(const short8*)(PWl + (size_t)(g * 16 + r) * 320 + k0);
      accp[g] = __builtin_amdgcn_mfma_f32_16x16x32_bf16(al, bh, accp[g], 0, 0, 0);
      accp[g] = __builtin_amdgcn_mfma_f32_16x16x32_bf16(ah, bl, accp[g], 0, 0, 0);
      accp[g] = __builtin_amdgcn_mfma_f32_16x16x32_bf16(ah, bh, accp[g], 0, 0, 0);
    }
  }
  // xp tile -> LDS bf16 hi/lo (rows mloc..mloc+15 written AND read by wave w;
  // DS ops in-order per wave => no barrier)
  #pragma unroll
  for (int g = 0; g < 4; g++)
    #pragma unroll
    for (int e = 0; e < 4; e++) {
      short h, l; bsplit(accp[g][e], h, l);
      XPH[mloc + q * 4 + e][g * 16 + r] = h;
      XPL[mloc + q * 4 + e][g * 16 + r] = l;
    }

  // ---- phase B: qkv both branches, K=64
  float4v acc[2][12];
  #pragma unroll
  for (int nf = 0; nf < 12; nf++) {
    float bv0 = lb[nf * 16 + r], bv1 = gb[nf * 16 + r];
    float4v t0 = {bv0, bv0, bv0, bv0};
    float4v t1 = {bv1, bv1, bv1, bv1};
    acc[0][nf] = t0; acc[1][nf] = t1;
  }
  #pragma unroll
  for (int ks = 0; ks < 2; ks++) {
    const int k0 = ks * 32 + q * 8;
    short8 ah = *(const short8*)&XPH[mloc + r][k0];
    short8 al = *(const short8*)&XPL[mloc + r][k0];
    #pragma unroll
    for (int nf = 0; nf < 12; nf++) {
      short8 bh0 = *(const short8*)(LWh + (size_t)(nf * 16 + r) * 64 + k0);
      short8 bl0 = *(const short8*)(LWl + (size_t)(nf * 16 + r) * 64 + k0);
      acc[0][nf] = __builtin_amdgcn_mfma_f32_16x16x32_bf16(al, bh0, acc[0][nf], 0, 0, 0);
      acc[0][nf] = __builtin_amdgcn_mfma_f32_16x16x32_bf16(ah, bl0, acc[0][nf], 0, 0, 0);
      acc[0][nf] = __builtin_amdgcn_mfma_f32_16x16x32_bf16(ah, bh0, acc[0][nf], 0, 0, 0);
      short8 bh1 = *(const short8*)(GWh + (size_t)(nf * 16 + r) * 64 + k0);
      short8 bl1 = *(const short8*)(GWl + (size_t)(nf * 16 + r) * 64 + k0);
      acc[1][nf] = __builtin_amdgcn_mfma_f32_16x16x32_bf16(al, bh1, acc[1][nf], 0, 0, 0);
      acc[1][nf] = __builtin_amdgcn_mfma_f32_16x16x32_bf16(ah, bl1, acc[1][nf], 0, 0, 0);
      acc[1][nf] = __builtin_amdgcn_mfma_f32_16x16x32_bf16(ah, bh1, acc[1][nf], 0, 0, 0);
    }
  }

  // ---- epilogue
  const int b = m0 >> 10;           // 64-row blocks never straddle a batch
  const int bh8 = b * 8;
  #pragma unroll
  for (int e = 0; e < 4; e++) {
    const int row = m0 + q * 4 + e;
    const int i = row & 1023;
    #pragma unroll
    for (int nf = 0; nf < 12; nf++) {
      qkv_l[(size_t)row * 192 + nf * 16 + r] = acc[0][nf][e];
      qkv_g[(size_t)row * 192 + nf * 16 + r] = acc[1][nf][e];
    }
    if (i % 3 == 0) {
      const int kk = i / 3;         // 0..341
      #pragma unroll
      for (int nf = 4; nf < 12; nf++) {
        const int col = nf * 16 + r;        // 64..191
        float v = acc[1][nf][e];
        short h, l; bsplit(v, h, l);
        if (col < 128) {                    // K rows
          const int ck = col - 64;
          const int hh = ck >> 3, d = ck & 7;
          KH[(size_t)(bh8 + hh) * 2816 + kk * 8 + d] = h;
          KL[(size_t)(bh8 + hh) * 2816 + kk * 8 + d] = l;
        } else {                            // V^T rows
          const int cv = col - 128;
          const int hh = cv >> 3, d = cv & 7;
          VTh[((size_t)(bh8 + hh) * 16 + d) * 352 + kk] = h;
          VTl[((size_t)(bh8 + hh) * 16 + d) * 352 + kk] = l;
        }
      }
    }
  }
}

// ---------------- attention: blocks [0,2048) = MFMA global attention,
// blocks [2048,2560) = local sliding-window attention (independent work).
// gattn block order: qt fastest => 16 consecutive blocks share (b,h) K/V.
// Note: KH pads kk>=342 are never initialized (poison) — safe because p is
// forced to 0 by the key<342 mask before any use; VT pads ARE initialized.
__global__ __launch_bounds__(256) void attn(
    const float* __restrict__ qkv_g, const float* __restrict__ qkv_l,
    const short* __restrict__ KH, const short* __restrict__ KL,
    const short* __restrict__ VTh, const short* __restrict__ VTl,
    float* __restrict__ o_g, float* __restrict__ pl, float* __restrict__ o_l)
{
  __shared__ short Pbuf[4][2][2][16][32];   // wave, parity, hi/lo, q, k
  const int u = blockIdx.x;
  if (u < 2048) {
    const int qt = u & 15, h = (u >> 4) & 7, b = u >> 7;
    const int w = threadIdx.x >> 6, lane = threadIdx.x & 63;
    const int quad = lane >> 4, r = lane & 15;
    const int bh = b * 8 + h;
    const int m0 = qt * 64 + w * 16;

    const short8 z8 = {0,0,0,0,0,0,0,0};
    short8 qh = z8, ql = z8;
    if (quad == 0) {
      const float* qp = qkv_g + (size_t)(b * 1024 + m0 + r) * 192 + h * 8;
      #pragma unroll
      for (int d = 0; d < 8; d++) { short hh, ll; bsplit(qp[d], hh, ll); qh[d]=hh; ql[d]=ll; }
    }
    const short* kbase  = KH + (size_t)bh * 2816;
    const short* klbase = KL + (size_t)bh * 2816;
    const short* vhbase = VTh + ((size_t)bh * 16 + r) * 352;
    const short* vlbase = VTl + ((size_t)bh * 16 + r) * 352;

    float4v oacc = {0.f, 0.f, 0.f, 0.f};

    for (int kc = 0; kc < 11; kc++) {
      short8 kh0 = z8, kl0 = z8, kh1 = z8, kl1 = z8;
      if (quad == 0) {
        kh0 = *(const short8*)(kbase  + (size_t)(kc * 32 + r) * 8);
        kl0 = *(const short8*)(klbase + (size_t)(kc * 32 + r) * 8);
        kh1 = *(const short8*)(kbase  + (size_t)(kc * 32 + 16 + r) * 8);
        kl1 = *(const short8*)(klbase + (size_t)(kc * 32 + 16 + r) * 8);
      }
      float4v s0 = {0.f,0.f,0.f,0.f}, s1 = {0.f,0.f,0.f,0.f};
      s0 = __builtin_amdgcn_mfma_f32_16x16x32_bf16(qh, kl0, s0, 0, 0, 0);
      s0 = __builtin_amdgcn_mfma_f32_16x16x32_bf16(ql, kh0, s0, 0, 0, 0);
      s0 = __builtin_amdgcn_mfma_f32_16x16x32_bf16(qh, kh0, s0, 0, 0, 0);
      s1 = __builtin_amdgcn_mfma_f32_16x16x32_bf16(qh, kl1, s1, 0, 0, 0);
      s1 = __builtin_amdgcn_mfma_f32_16x16x32_bf16(ql, kh1, s1, 0, 0, 0);
      s1 = __builtin_amdgcn_mfma_f32_16x16x32_bf16(qh, kh1, s1, 0, 0, 0);

      const int par = kc & 1;
      const int key0 = kc * 32 + r, key1 = key0 + 16;
      #pragma unroll
      for (int e = 0; e < 4; e++) {
        float p0 = (key0 < 342) ? __expf(s0[e] * INV_SQRT8) : 0.f;
        float p1 = (key1 < 342) ? __expf(s1[e] * INV_SQRT8) : 0.f;
        short h0, l0, h1, l1; bsplit(p0, h0, l0); bsplit(p1, h1, l1);
        const int qloc = quad * 4 + e;
        Pbuf[w][par][0][qloc][r]      = h0;
        Pbuf[w][par][0][qloc][16 + r] = h1;
        Pbuf[w][par][1][qloc][r]      = l0;
        Pbuf[w][par][1][qloc][16 + r] = l1;
      }
      // Same-wave LDS transpose read (DS ops in-order per wave; no barrier).
      short8 pA = *(const short8*)&Pbuf[w][par][0][r][quad * 8];
      short8 pB = *(const short8*)&Pbuf[w][par][1][r][quad * 8];
      short8 vh = *(const short8*)(vhbase + kc * 32 + quad * 8);
      short8 vl = *(const short8*)(vlbase + kc * 32 + quad * 8);
      oacc = __builtin_amdgcn_mfma_f32_16x16x32_bf16(pA, vl, oacc, 0, 0, 0);
      oacc = __builtin_amdgcn_mfma_f32_16x16x32_bf16(pB, vh, oacc, 0, 0, 0);
      oacc = __builtin_amdgcn_mfma_f32_16x16x32_bf16(pA, vh, oacc, 0, 0, 0);
    }

    #pragma unroll
    for (int e = 0; e < 4; e++) {
      const int orow = b * 1024 + m0 + quad * 4 + e;
      if (r < 8)       o_g[(size_t)orow * 64 + h * 8 + r] = oacc[e];
      else if (r == 8) pl[(size_t)orow * 8 + h] = oacc[e];
    }
  } else {
    int t = (u - 2048) * 256 + threadIdx.x;   // 131072
    int h = t & 7;
    int i = (t >> 3) & 1023;
    int b = t >> 13;
    const float* base = qkv_l + (size_t)b * 1024 * 192;
    const float* qp = base + (size_t)i * 192 + h * 8;
    float4 q0 = ld4(qp), q1 = ld4(qp + 4);
    float l = 0.f;
    float4 o0 = make_float4(0.f, 0.f, 0.f, 0.f);
    float4 o1 = make_float4(0.f, 0.f, 0.f, 0.f);
    int jlo = i - 5; if (jlo < 0) jlo = 0;
    int jhi = i + 5; if (jhi > 1023) jhi = 1023;
    for (int j = jlo; j <= jhi; j++) {
      const float* kp = base + (size_t)j * 192 + 64 + h * 8;
      float4 k0 = ld4(kp), k1 = ld4(kp + 4);
      float s = q0.x * k0.x + q0.y * k0.y + q0.z * k0.z + q0.w * k0.w
              + q1.x * k1.x + q1.y * k1.y + q1.z * k1.z + q1.w * k1.w;
      float p = __expf(s * INV_SQRT8);
      l += p;
      float4 v0 = ld4(kp + 64), v1 = ld4(kp + 68);
      o0 = f4fma(p, v0, o0);
      o1 = f4fma(p, v1, o1);
    }
    float inv = 1.f / l;
    float* op = o_l + (size_t)(b * 1024 + i) * 64 + h * 8;
    float4 r0, r1;
    r0.x = o0.x * inv; r0.y = o0.y * inv; r0.z = o0.z * inv; r0.w = o0.w * inv;
    r1.x = o1.x * inv; r1.y = o1.y * inv; r1.z = o1.z * inv; r1.w = o1.w * inv;
    *(float4*)op = r0;
    *(float4*)(op + 4) = r1;
  }
}

// ---------------- Fusion GEMM + score + pool partials, fused via LDS.
// Block = 64 rows (grid 256). Wave w: rows w*16..+16, ALL 64 cols (4 frags).
// Diag-key + 1/l normalization folded into A-load.
__global__ __launch_bounds__(256) void gemm_fuse_score(
    const float* __restrict__ o_l, const float* __restrict__ o_g,
    const float* __restrict__ pl, const float* __restrict__ qkv_g,
    const short* __restrict__ Wh, const short* __restrict__ Wl,
    const float* __restrict__ bc,
    const float* __restrict__ pw1, const float* __restrict__ pb1,
    const float* __restrict__ pw2, const float* __restrict__ pb2,
    float* __restrict__ num, float* __restrict__ den)
{
  __shared__ float Ls[64][68];
  __shared__ float partial[4][64];
  const int tid = threadIdx.x;
  const int lane = tid & 63, w = tid >> 6;
  const int quad = lane >> 4, r = lane & 15;
  const int bx = blockIdx.x;
  const int m0 = bx * 64 + w * 16;

  float4v acc[4];
  #pragma unroll
  for (int g = 0; g < 4; g++) {
    float bv = bc[g * 16 + r];
    float4v t = {bv, bv, bv, bv};
    acc[g] = t;
  }

  #pragma unroll
  for (int ks = 0; ks < 4; ks++) {
    const int k0 = ks * 32 + quad * 8;
    const int row = m0 + r;
    float av[8];
    if (ks < 2) {   // local branch, already normalized
      const float* ap = o_l + (size_t)row * 64 + k0;
      float4 f0 = ld4(ap), f1 = ld4(ap + 4);
      av[0]=f0.x; av[1]=f0.y; av[2]=f0.z; av[3]=f0.w;
      av[4]=f1.x; av[5]=f1.y; av[6]=f1.z; av[7]=f1.w;
    } else {        // global branch: unnormalized O + diag + normalize
      const int off = k0 - 64;
      const int h = off >> 3;
      const float* op = o_g + (size_t)row * 64 + off;
      float4 O0 = ld4(op), O1 = ld4(op + 4);
      float l = pl[(size_t)row * 8 + h];
      const int i = row & 1023;
      if (i % 3 != 0) {
        const float* base = qkv_g + (size_t)row * 192;
        const float* qp = base + h * 8;
        const float* kpp = base + 64 + h * 8;
        const float* vp = base + 128 + h * 8;
        float4 q0 = ld4(qp), q1 = ld4(qp + 4);
        float4 k0v = ld4(kpp), k1v = ld4(kpp + 4);
        float s = q0.x*k0v.x + q0.y*k0v.y + q0.z*k0v.z + q0.w*k0v.w
                + q1.x*k1v.x + q1.y*k1v.y + q1.z*k1v.z + q1.w*k1v.w;
        float p = __expf(s * INV_SQRT8);
        float4 v0 = ld4(vp), v1 = ld4(vp + 4);
        O0 = f4fma(p, v0, O0); O1 = f4fma(p, v1, O1);
        l += p;
      }
      float inv = 1.f / l;
      av[0]=O0.x*inv; av[1]=O0.y*inv; av[2]=O0.z*inv; av[3]=O0.w*inv;
      av[4]=O1.x*inv; av[5]=O1.y*inv; av[6]=O1.z*inv; av[7]=O1.w*inv;
    }
    short8 ah, al;
    #pragma unroll
    for (int i2 = 0; i2 < 8; i2++) { short h2, l2; bsplit(av[i2], h2, l2); ah[i2]=h2; al[i2]=l2; }
    #pragma unroll
    for (int g = 0; g < 4; g++) {
      short8 bh = *(const short8*)(Wh + (size_t)(g * 16 + r) * 128 + k0);
      short8 bl = *(const short8*)(Wl + (size_t)(g * 16 + r) * 128 + k0);
      acc[g] = __builtin_amdgcn_mfma_f32_16x16x32_bf16(al, bh, acc[g], 0, 0, 0);
      acc[g] = __builtin_amdgcn_mfma_f32_16x16x32_bf16(ah, bl, acc[g], 0, 0, 0);
      acc[g] = __builtin_amdgcn_mfma_f32_16x16x32_bf16(ah, bh, acc[g], 0, 0, 0);
    }
  }

  // park C-tile in LDS: Ls[row_local][col]
  #pragma unroll
  for (int g = 0; g < 4; g++)
    #pragma unroll
    for (int e = 0; e < 4; e++)
      Ls[w * 16 + quad * 4 + e][g * 16 + r] = acc[g][e];
  __syncthreads();

  // score phase. lane = row_local.
  float4 fr[16];
  #pragma unroll
  for (int e = 0; e < 16; e++) fr[e] = *(float4*)&Ls[lane][e * 4];

  float psc = 0.f;
  #pragma unroll
  for (int jj = 0; jj < 8; jj++) {
    const int j = w * 8 + jj;
    const float* wr = pw1 + j * 64;   // wave-uniform -> s_load
    float hj = pb1[j];
    #pragma unroll
    for (int e = 0; e < 16; e++) {
      float4 wv = ld4(wr + e * 4);
      hj += fr[e].x * wv.x + fr[e].y * wv.y + fr[e].z * wv.z + fr[e].w * wv.w;
    }
    float e2 = __expf(2.f * hj);
    psc += ((e2 - 1.f) / (e2 + 1.f)) * pw2[j];   // tanh via exp
  }
  partial[w][lane] = psc;
  __syncthreads();
  if (w == 0) {
    const int b = bx >> 4;
    float sc = pb2[0] + partial[0][lane] + partial[1][lane]
             + partial[2][lane] + partial[3][lane];
    float p = __expf(sc);
    #pragma unroll
    for (int e = 0; e < 16; e++) {
      Ls[lane][e*4+0] = p * fr[e].x; Ls[lane][e*4+1] = p * fr[e].y;
      Ls[lane][e*4+2] = p * fr[e].z; Ls[lane][e*4+3] = p * fr[e].w;
    }
    // single wave: DS ops in order, no barrier needed
    float colsum = 0.f;
    #pragma unroll 8
    for (int s = 0; s < 64; s++) colsum += Ls[s][lane];
    atomicAdd(&num[b * 64 + lane], colsum);
    float ps = p;
    #pragma unroll
    for (int off = 32; off > 0; off >>= 1)
      ps += __shfl_xor(ps, off, 64);
    if (lane == 0) atomicAdd(&den[b], ps);
  }
}

// ---------------- finalize: out = num/den
__global__ __launch_bounds__(1024) void finalize(
    const float* __restrict__ num, const float* __restrict__ den,
    float* __restrict__ out)
{
  int t = threadIdx.x;   // 1024 = 16*64
  out[t] = num[t] / den[t >> 6];
}

extern "C" void kernel_launch(void* const* d_in, const int* in_sizes, int n_in,
                              void* d_out, int out_size, void* d_ws, size_t ws_size,
                              hipStream_t stream)
{
  const float* x          = (const float*)d_in[0];
  const float* proj_w     = (const float*)d_in[1];
  const float* proj_b     = (const float*)d_in[2];
  const float* loc_in_w   = (const float*)d_in[3];
  const float* loc_in_b   = (const float*)d_in[4];
  const float* loc_out_w  = (const float*)d_in[5];
  const float* loc_out_b  = (const float*)d_in[6];
  const float* glob_in_w  = (const float*)d_in[7];
  const float* glob_in_b  = (const float*)d_in[8];
  const float* glob_out_w = (const float*)d_in[9];
  const float* glob_out_b = (const float*)d_in[10];
  const float* fusion_w   = (const float*)d_in[11];
  const float* fusion_b   = (const float*)d_in[12];
  const float* pw1        = (const float*)d_in[13];
  const float* pb1        = (const float*)d_in[14];
  const float* pw2        = (const float*)d_in[15];
  const float* pb2        = (const float*)d_in[16];

  float* ws = (float*)d_ws;
  // Layout (float offsets), same constants as R11 (xph/xpl region now unused):
  //  qkv_g    [0, 3145728)
  //  qkv_l    [4587520, 7733248)
  //  o_l      [7733248, 8781824)
  //  o_g      [8781824, 9830400)
  //  pl       [9830400, 9961472)
  //  KH/KL    shorts at 9961472 / 10141696 (360448 each)
  //  VTh/VTl  shorts at 10321920 / 10682368 (720896 each)
  //  bc       [11042816, 11042880)
  //  num/den  [11042880, 11043920)
  //  wb       shorts at 11043920 (112640)
  float* qkv_g = ws;
  float* qkv_l = ws + 4587520;
  float* o_l   = ws + 7733248;
  float* o_g   = ws + 8781824;
  float* pl    = ws + 9830400;
  short* KH    = (short*)(ws + 9961472);
  short* KL    = (short*)(ws + 10141696);
  short* VTh   = (short*)(ws + 10321920);
  short* VTl   = (short*)(ws + 10682368);
  float* bc    = ws + 11042816;
  float* numden= ws + 11042880;
  float* num   = numden;
  float* den   = numden + 1024;
  short* wb    = (short*)(ws + 11043920);
  short* projh = wb;           short* projl = wb + 20480;
  short* linh  = wb + 40960;   short* linl  = wb + 53248;
  short* ginh  = wb + 65536;   short* ginl  = wb + 77824;
  short* wfh   = wb + 90112;   short* wfl   = wb + 98304;
  float* out   = (float*)d_out;

  dim3 blk(256);
  // 1: weight split + fused fusion weights + combined bias + zeros + VT pads
  //    idx range = 53248 + 370688 = 423936 = 1656 * 256
  prep_w<<<1656, blk, 0, stream>>>(proj_w, loc_in_w, glob_in_w, fusion_w,
                                   loc_out_w, glob_out_w, loc_out_b, glob_out_b,
                                   fusion_b, wb, bc, numden, VTh, VTl);
  // 2: fused proj + qkv GEMM; writes qkv_l, qkv_g, KH/KL, VTh/VTl
  gemm_proj_qkv<<<256, blk, 0, stream>>>(
      x, projh, projl, proj_b, linh, linl, ginh, ginl, loc_in_b, glob_in_b,
      qkv_l, qkv_g, KH, KL, VTh, VTl);
  // 3: global MFMA attention (2048 blocks) + local attention (512 blocks)
  attn<<<2560, blk, 0, stream>>>(qkv_g, qkv_l, KH, KL, VTh, VTl, o_g, pl, o_l);
  // 4: fusion GEMM + score + pool partials
  gemm_fuse_score<<<256, blk, 0, stream>>>(
      o_l, o_g, pl, qkv_g, wfh, wfl, bc, pw1, pb1, pw2, pb2, num, den);
  // 5: finalize out = num/den
  finalize<<<1, dim3(1024), 0, stream>>>(num, den, out);
}